// Round 6
// baseline (419.301 us; speedup 1.0000x reference)
//
#include <hip/hip_runtime.h>
#include <math.h>

// Problem constants
#define BB 512
#define TT 2048
#define AA 16
#define NTOT (512LL * 2048LL * 16LL)   // 16,777,216
#define GAMMA 0.99f
#define GLAM  0.9405f                  // gamma * lam, matches python double->f32
#define ENTC  1.4189385332046727f      // 0.5 + 0.5*log(2*pi)

#define QPB 4                          // blocks per batch row (phase-2 split)
#define NB1 (BB * QPB)                 // 2048 blocks for fused kernel
#define NB3 4096                       // blocks for out kernel (4 f32x4/thread)

typedef float f32x4 __attribute__((ext_vector_type(4)));

// Volatile-asm 16B global loads (kept from r5: proven correct; ordering and
// liveness immune to the source-pipeline collapse seen in r1/r2/r4).
#define NT_LOAD(dst, off, base) \
    asm volatile("global_load_dwordx4 %0, %1, %2 nt" \
                 : "=v"(dst) : "v"(off), "s"(base))
#define C_LOAD(dst, off, base) \
    asm volatile("global_load_dwordx4 %0, %1, %2" \
                 : "=v"(dst) : "v"(off), "s"(base))
#define VM_WAIT_FENCE(n) do { \
    asm volatile("s_waitcnt vmcnt(" #n ")"); \
    __builtin_amdgcn_sched_barrier(0); } while (0)

// ---------------------------------------------------------------------------
__device__ __forceinline__ float obj1(float x, float m, float s,
                                      float om, float os, float ad)
{
    float rs  = __builtin_amdgcn_rcpf(s);
    float ros = __builtin_amdgcn_rcpf(os);
    float z   = (x - m) * rs;
    float zo  = (x - om) * ros;
    float d   = 0.5f * (zo * zo - z * z);
    float ratio = os * rs * __expf(d);
    return fminf(ad * ratio, ad * 0.8f);     // clipped == 0.8 (faithful clip bug)
}

__device__ __forceinline__ double obj4d(f32x4 m, f32x4 s, f32x4 om, f32x4 os,
                                        f32x4 x, float ad)
{
    float o0 = obj1(x.x, m.x, s.x, om.x, os.x, ad);
    float o1 = obj1(x.y, m.y, s.y, om.y, os.y, ad);
    float o2 = obj1(x.z, m.z, s.z, om.z, os.z, ad);
    float o3 = obj1(x.w, m.w, s.w, om.w, os.w, ad);
    return (double)o0 + (double)o1 + (double)o2 + (double)o3;
}

// ---------------------------------------------------------------------------
// K1: FUSED GAE + PPO objective + final mean reduction.
//  - XCD-bijective swizzle (2048 % 8 == 0): the 4 quarter-blocks of each
//    row land on the SAME XCD, so the redundant row-scan reads hit that
//    XCD's L2 instead of refetching 4x.
//  - mu is now a CACHED load (L3-stable set sigma+mu+scan+out ~= 212MB
//    < 256MB L3); om/os/x stay NT (streamed once, never reused).
//  - Last-arriving block (device-scope acq_rel counter) reduces the 2048
//    partials to the final mean, so K2 reads 8 bytes instead of 32MB.
// ---------------------------------------------------------------------------
__global__ __launch_bounds__(512) void gae_obj_kernel(
    const float* __restrict__ rewards, const float* __restrict__ vout,
    const int* __restrict__ dones,
    const float* __restrict__ mu, const float* __restrict__ sigma,
    const float* __restrict__ old_mu, const float* __restrict__ old_sigma,
    const float* __restrict__ actions,
    double* __restrict__ partials, unsigned int* __restrict__ counter,
    double* __restrict__ meanPtr)
{
    __shared__ float  adv_s[TT];          // 8 KB
    __shared__ float  wA[8], wB[8];
    __shared__ double wsum[8];
    __shared__ int    winner_s;

    // XCD-aware bijection: dispatch slot -> work id. Consecutive dispatch
    // slots round-robin XCDs; this gives XCD k the contiguous work range
    // [k*256,(k+1)*256) = rows [k*64,(k+1)*64), quarters together.
    const uint32_t wg = ((blockIdx.x & 7u) << 8) + ((uint32_t)blockIdx.x >> 3);
    const int b    = (int)(wg >> 2);      // batch row
    const int q    = (int)(wg & 3u);      // quarter of the row
    const int tid  = threadIdx.x;
    const int lane = tid & 63;
    const int wave = tid >> 6;

    // ---------------- Phase 1: full-row GAE scan into LDS ----------------
    {
        const float* rw = rewards + (size_t)b * TT;
        const float* V  = vout    + (size_t)b * (TT + 1);
        const int*   dn = dones   + (size_t)b * TT;

        const int t_lo = TT - 4 - 4 * tid;          // multiple of 4, >= 0

        f32x4 r4 = *(const f32x4*)(rw + t_lo);
        int4  d4 = *(const int4*)(dn + t_lo);
        int   dt = (tid == 0) ? 1 : dn[t_lo + 4];   // dn[2048] OOB for tid 0; unused there
        float vv[5];
        #pragma unroll
        for (int j = 0; j < 5; ++j) vv[j] = V[t_lo + j];  // V[2048] valid (T+1 cols)

        float rr[4] = {r4.x, r4.y, r4.z, r4.w};
        int   dd[5] = {d4.x, d4.y, d4.z, d4.w, dt};

        float ak[4], bk[4];
        float SA = 1.f, SB = 0.f;                   // segment composite (earliest-first)
        #pragma unroll
        for (int k = 0; k < 4; ++k) {
            // u = tid*4 + k ; t = TT-1-u = t_lo + (3-k)
            const int j = 3 - k;
            float bu = rr[j] + GAMMA * vv[j + 1] - vv[j];
            float au = GLAM * (1.f - (float)dd[j + 1]);
            if (k == 0 && tid == 0) { au = 0.f; bu = 0.f; }   // u == 0
            ak[k] = au; bk[k] = bu;
            SB = au * SB + bu;
            SA = au * SA;
        }

        #pragma unroll
        for (int off = 1; off < 64; off <<= 1) {
            float pA = __shfl_up(SA, off, 64);
            float pB = __shfl_up(SB, off, 64);
            if (lane >= off) { SB = SA * pB + SB; SA = SA * pA; }
        }

        if (lane == 63) { wA[wave] = SA; wB[wave] = SB; }
        __syncthreads();

        float PA = 1.f, PB = 0.f;
        for (int w = 0; w < wave; ++w) {
            float aw = wA[w], bw = wB[w];
            PB = aw * PB + bw;
            PA = aw * PA;
        }

        float EA = __shfl_up(SA, 1, 64);
        float EB = __shfl_up(SB, 1, 64);
        if (lane == 0) { EA = 1.f; EB = 0.f; }

        float x = EA * PB + EB;
        float outb[4];
        #pragma unroll
        for (int k = 0; k < 4; ++k) {
            x = ak[k] * x + bk[k];
            outb[3 - k] = x;                        // t = t_lo + (3-k)
        }
        *(f32x4*)(adv_s + t_lo) = (f32x4){outb[0], outb[1], outb[2], outb[3]};
    }
    __syncthreads();

    // ---------------- Phase 2: objective over this block's quarter --------
    const size_t basef4 = (size_t)b * 8192 + (size_t)q * 2048;
    const f32x4* m4  = (const f32x4*)mu        + basef4;
    const f32x4* s4  = (const f32x4*)sigma     + basef4;
    const f32x4* om4 = (const f32x4*)old_mu    + basef4;
    const f32x4* os4 = (const f32x4*)old_sigma + basef4;
    const f32x4* x4  = (const f32x4*)actions   + basef4;
    const float* advq = adv_s + q * 512;

    const int ai = tid >> 2;
    const float Aa = advq[ai];
    const float Ba = advq[ai + 128];
    const float Ca = advq[ai + 256];
    const float Da = advq[ai + 384];

    const uint32_t o0 = (uint32_t)tid * 16u;
    const uint32_t o1 = o0 + 512u * 16u;
    const uint32_t o2 = o0 + 1024u * 16u;
    const uint32_t o3 = o0 + 1536u * 16u;

    f32x4 Am, As, Aom, Aos, Ax;
    f32x4 Bm, Bs, Bom, Bos, Bx;
    f32x4 Cm, Cs, Com, Cos, Cx;
    f32x4 Dm, Ds, Dom, Dos, Dx;

    // 20 loads in flight per thread; mu+sigma cached, om/os/x streamed
    C_LOAD(Am, o0, m4);  C_LOAD(As, o0, s4);  NT_LOAD(Aom, o0, om4);
    NT_LOAD(Aos, o0, os4);  NT_LOAD(Ax, o0, x4);
    C_LOAD(Bm, o1, m4);  C_LOAD(Bs, o1, s4);  NT_LOAD(Bom, o1, om4);
    NT_LOAD(Bos, o1, os4);  NT_LOAD(Bx, o1, x4);
    C_LOAD(Cm, o2, m4);  C_LOAD(Cs, o2, s4);  NT_LOAD(Com, o2, om4);
    NT_LOAD(Cos, o2, os4);  NT_LOAD(Cx, o2, x4);
    C_LOAD(Dm, o3, m4);  C_LOAD(Ds, o3, s4);  NT_LOAD(Dom, o3, om4);
    NT_LOAD(Dos, o3, os4);  NT_LOAD(Dx, o3, x4);

    VM_WAIT_FENCE(15);
    double lsum = obj4d(Am, As, Aom, Aos, Ax, Aa);
    VM_WAIT_FENCE(10);
    lsum += obj4d(Bm, Bs, Bom, Bos, Bx, Ba);
    VM_WAIT_FENCE(5);
    lsum += obj4d(Cm, Cs, Com, Cos, Cx, Ca);
    VM_WAIT_FENCE(0);
    lsum += obj4d(Dm, Ds, Dom, Dos, Dx, Da);

    // block reduce (8 waves)
    #pragma unroll
    for (int off = 32; off > 0; off >>= 1)
        lsum += __shfl_down(lsum, off, 64);
    if (lane == 0) wsum[wave] = lsum;
    __syncthreads();
    if (tid == 0) {
        double t = 0.0;
        #pragma unroll
        for (int w = 0; w < 8; ++w) t += wsum[w];
        partials[wg] = t;
        // release: partials store above becomes visible to whichever block
        // observes this add with acquire.
        unsigned int old = __hip_atomic_fetch_add(counter, 1u,
                                                  __ATOMIC_ACQ_REL,
                                                  __HIP_MEMORY_SCOPE_AGENT);
        winner_s = (old == (unsigned int)(NB1 - 1)) ? 1 : 0;
    }
    __syncthreads();

    // Last block reduces all 2048 partials -> mean (K2 then reads 8 bytes).
    if (winner_s) {
        double s = 0.0;
        #pragma unroll
        for (int i = 0; i < 4; ++i) s += partials[tid + 512 * i];
        #pragma unroll
        for (int off = 32; off > 0; off >>= 1)
            s += __shfl_down(s, off, 64);
        if (lane == 0) wsum[wave] = s;          // safe reuse: all synced above
        __syncthreads();
        if (tid == 0) {
            double t = 0.0;
            #pragma unroll
            for (int w = 0; w < 8; ++w) t += wsum[w];
            *meanPtr = t / (double)NTOT;
        }
    }
}

// ---------------------------------------------------------------------------
// K2: out[i] = mean + log(sigma[i]) + ENTC.
// mean is a single f64 read; sigma is L3-warm from K1's cached loads.
// 4096 blocks x 256 thr x 4 independent f32x4; NT stores (write-once).
// ---------------------------------------------------------------------------
__global__ __launch_bounds__(256) void out_kernel(
    const float* __restrict__ sigma, const double* __restrict__ meanPtr,
    float* __restrict__ out)
{
    const int tid = threadIdx.x;
    const uint32_t Q = (uint32_t)(NTOT / 4 / 4);        // 1,048,576 f32x4/stream
    const uint32_t v = (uint32_t)blockIdx.x * 256u + (uint32_t)tid;  // < Q

    const f32x4* s4 = (const f32x4*)sigma;
    f32x4* o4 = (f32x4*)out;

    f32x4 a = s4[v];
    f32x4 b = s4[v + Q];
    f32x4 c = s4[v + 2u * Q];
    f32x4 d = s4[v + 3u * Q];
    const float mc = (float)(*meanPtr) + ENTC;          // mean + ENTC

    f32x4 oa, ob, oc, od;
    oa.x = mc + __logf(a.x);  oa.y = mc + __logf(a.y);
    oa.z = mc + __logf(a.z);  oa.w = mc + __logf(a.w);
    ob.x = mc + __logf(b.x);  ob.y = mc + __logf(b.y);
    ob.z = mc + __logf(b.z);  ob.w = mc + __logf(b.w);
    oc.x = mc + __logf(c.x);  oc.y = mc + __logf(c.y);
    oc.z = mc + __logf(c.z);  oc.w = mc + __logf(c.w);
    od.x = mc + __logf(d.x);  od.y = mc + __logf(d.y);
    od.z = mc + __logf(d.z);  od.w = mc + __logf(d.w);

    __builtin_nontemporal_store(oa, o4 + v);
    __builtin_nontemporal_store(ob, o4 + v + Q);
    __builtin_nontemporal_store(oc, o4 + v + 2u * Q);
    __builtin_nontemporal_store(od, o4 + v + 3u * Q);
}

// ---------------------------------------------------------------------------
extern "C" void kernel_launch(void* const* d_in, const int* in_sizes, int n_in,
                              void* d_out, int out_size, void* d_ws, size_t ws_size,
                              hipStream_t stream) {
    const float* rewards   = (const float*)d_in[0];   // [B,T]
    const float* critic    = (const float*)d_in[1];   // [B,T+1]
    const float* mu        = (const float*)d_in[2];   // [B,T,A]
    const float* sigma     = (const float*)d_in[3];
    const float* old_mu    = (const float*)d_in[4];
    const float* old_sigma = (const float*)d_in[5];
    const float* actions   = (const float*)d_in[6];
    const int*   dones     = (const int*)d_in[7];     // [B,T]
    float* out = (float*)d_out;

    char* ws = (char*)d_ws;
    double*       meanPtr  = (double*)ws;             // 8 B
    unsigned int* counter  = (unsigned int*)(ws + 64);// 4 B
    double*       partials = (double*)(ws + 4096);    // NB1 * 8 B = 16 KB

    hipMemsetAsync(counter, 0, sizeof(unsigned int), stream);
    gae_obj_kernel<<<NB1, 512, 0, stream>>>(rewards, critic, dones,
                                            mu, sigma, old_mu, old_sigma,
                                            actions, partials, counter, meanPtr);
    out_kernel<<<NB3, 256, 0, stream>>>(sigma, meanPtr, out);
}

// Round 7
// 331.311 us; speedup vs baseline: 1.2656x; 1.2656x over previous
//
#include <hip/hip_runtime.h>
#include <math.h>

// Problem constants
#define BB 512
#define TT 2048
#define AA 16
#define NTOT (512LL * 2048LL * 16LL)   // 16,777,216
#define GAMMA 0.99f
#define GLAM  0.9405f                  // gamma * lam, matches python double->f32
#define ENTC  1.4189385332046727f      // 0.5 + 0.5*log(2*pi)

#define QPB 4                          // blocks per batch row (phase-2 split)
#define NB1 (BB * QPB)                 // 2048 blocks for fused kernel
#define NB3 2048                       // blocks for out kernel (8 f32x4/thread)

typedef float f32x4 __attribute__((ext_vector_type(4)));

// Volatile-asm 16B global loads (proven r5: ordering and liveness immune to
// the source-pipeline collapse seen in r1/r2/r4).
#define NT_LOAD(dst, off, base) \
    asm volatile("global_load_dwordx4 %0, %1, %2 nt" \
                 : "=v"(dst) : "v"(off), "s"(base))
#define C_LOAD(dst, off, base) \
    asm volatile("global_load_dwordx4 %0, %1, %2" \
                 : "=v"(dst) : "v"(off), "s"(base))
#define VM_WAIT_FENCE(n) do { \
    asm volatile("s_waitcnt vmcnt(" #n ")"); \
    __builtin_amdgcn_sched_barrier(0); } while (0)

// ---------------------------------------------------------------------------
__device__ __forceinline__ float obj1(float x, float m, float s,
                                      float om, float os, float ad)
{
    float rs  = __builtin_amdgcn_rcpf(s);
    float ros = __builtin_amdgcn_rcpf(os);
    float z   = (x - m) * rs;
    float zo  = (x - om) * ros;
    float d   = 0.5f * (zo * zo - z * z);
    float ratio = os * rs * __expf(d);
    return fminf(ad * ratio, ad * 0.8f);     // clipped == 0.8 (faithful clip bug)
}

__device__ __forceinline__ double obj4d(f32x4 m, f32x4 s, f32x4 om, f32x4 os,
                                        f32x4 x, float ad)
{
    float o0 = obj1(x.x, m.x, s.x, om.x, os.x, ad);
    float o1 = obj1(x.y, m.y, s.y, om.y, os.y, ad);
    float o2 = obj1(x.z, m.z, s.z, om.z, os.z, ad);
    float o3 = obj1(x.w, m.w, s.w, om.w, os.w, ad);
    return (double)o0 + (double)o1 + (double)o2 + (double)o3;
}

// ---------------------------------------------------------------------------
// K1: FUSED GAE + PPO objective. r5 body (proven 83.5us) + XCD swizzle
// (r6: FETCH 188.6->170MB) + RELAXED f64 atomic total (r1-proven cheap;
// r6's ACQ_REL release per block emitted L2 writeback/invalidate -> 2.3x
// regression, WRITE +55MB. Relaxed = no fences, determinism verified r1).
// ---------------------------------------------------------------------------
__global__ __launch_bounds__(512) void gae_obj_kernel(
    const float* __restrict__ rewards, const float* __restrict__ vout,
    const int* __restrict__ dones,
    const float* __restrict__ mu, const float* __restrict__ sigma,
    const float* __restrict__ old_mu, const float* __restrict__ old_sigma,
    const float* __restrict__ actions,
    double* __restrict__ total)
{
    __shared__ float  adv_s[TT];          // 8 KB
    __shared__ float  wA[8], wB[8];
    __shared__ double wsum[8];

    // XCD-bijective swizzle (2048 % 8 == 0): consecutive dispatch slots
    // round-robin XCDs; this gives XCD k contiguous rows, so the 4
    // quarter-blocks of a row share one XCD's L2 (scan reads become hits).
    const uint32_t wg = ((blockIdx.x & 7u) << 8) + ((uint32_t)blockIdx.x >> 3);
    const int b    = (int)(wg >> 2);      // batch row
    const int q    = (int)(wg & 3u);      // quarter of the row
    const int tid  = threadIdx.x;
    const int lane = tid & 63;
    const int wave = tid >> 6;

    // ---------------- Phase 1: full-row GAE scan into LDS ----------------
    {
        const float* rw = rewards + (size_t)b * TT;
        const float* V  = vout    + (size_t)b * (TT + 1);
        const int*   dn = dones   + (size_t)b * TT;

        const int t_lo = TT - 4 - 4 * tid;          // multiple of 4, >= 0

        f32x4 r4 = *(const f32x4*)(rw + t_lo);
        int4  d4 = *(const int4*)(dn + t_lo);
        int   dt = (tid == 0) ? 1 : dn[t_lo + 4];   // dn[2048] OOB for tid 0; unused there
        float vv[5];
        #pragma unroll
        for (int j = 0; j < 5; ++j) vv[j] = V[t_lo + j];  // V[2048] valid (T+1 cols)

        float rr[4] = {r4.x, r4.y, r4.z, r4.w};
        int   dd[5] = {d4.x, d4.y, d4.z, d4.w, dt};

        float ak[4], bk[4];
        float SA = 1.f, SB = 0.f;                   // segment composite (earliest-first)
        #pragma unroll
        for (int k = 0; k < 4; ++k) {
            // u = tid*4 + k ; t = TT-1-u = t_lo + (3-k)
            const int j = 3 - k;
            float bu = rr[j] + GAMMA * vv[j + 1] - vv[j];
            float au = GLAM * (1.f - (float)dd[j + 1]);
            if (k == 0 && tid == 0) { au = 0.f; bu = 0.f; }   // u == 0
            ak[k] = au; bk[k] = bu;
            SB = au * SB + bu;
            SA = au * SA;
        }

        #pragma unroll
        for (int off = 1; off < 64; off <<= 1) {
            float pA = __shfl_up(SA, off, 64);
            float pB = __shfl_up(SB, off, 64);
            if (lane >= off) { SB = SA * pB + SB; SA = SA * pA; }
        }

        if (lane == 63) { wA[wave] = SA; wB[wave] = SB; }
        __syncthreads();

        float PA = 1.f, PB = 0.f;
        for (int w = 0; w < wave; ++w) {
            float aw = wA[w], bw = wB[w];
            PB = aw * PB + bw;
            PA = aw * PA;
        }

        float EA = __shfl_up(SA, 1, 64);
        float EB = __shfl_up(SB, 1, 64);
        if (lane == 0) { EA = 1.f; EB = 0.f; }

        float x = EA * PB + EB;
        float outb[4];
        #pragma unroll
        for (int k = 0; k < 4; ++k) {
            x = ak[k] * x + bk[k];
            outb[3 - k] = x;                        // t = t_lo + (3-k)
        }
        *(f32x4*)(adv_s + t_lo) = (f32x4){outb[0], outb[1], outb[2], outb[3]};
    }
    __syncthreads();

    // ---------------- Phase 2: objective over this block's quarter --------
    const size_t basef4 = (size_t)b * 8192 + (size_t)q * 2048;
    const f32x4* m4  = (const f32x4*)mu        + basef4;
    const f32x4* s4  = (const f32x4*)sigma     + basef4;
    const f32x4* om4 = (const f32x4*)old_mu    + basef4;
    const f32x4* os4 = (const f32x4*)old_sigma + basef4;
    const f32x4* x4  = (const f32x4*)actions   + basef4;
    const float* advq = adv_s + q * 512;

    const int ai = tid >> 2;
    const float Aa = advq[ai];
    const float Ba = advq[ai + 128];
    const float Ca = advq[ai + 256];
    const float Da = advq[ai + 384];

    const uint32_t o0 = (uint32_t)tid * 16u;
    const uint32_t o1 = o0 + 512u * 16u;
    const uint32_t o2 = o0 + 1024u * 16u;
    const uint32_t o3 = o0 + 1536u * 16u;

    f32x4 Am, As, Aom, Aos, Ax;
    f32x4 Bm, Bs, Bom, Bos, Bx;
    f32x4 Cm, Cs, Com, Cos, Cx;
    f32x4 Dm, Ds, Dom, Dos, Dx;

    // 20 loads in flight per thread; sigma cached (reused by K2), rest NT
    NT_LOAD(Am, o0, m4);  C_LOAD(As, o0, s4);  NT_LOAD(Aom, o0, om4);
    NT_LOAD(Aos, o0, os4);  NT_LOAD(Ax, o0, x4);
    NT_LOAD(Bm, o1, m4);  C_LOAD(Bs, o1, s4);  NT_LOAD(Bom, o1, om4);
    NT_LOAD(Bos, o1, os4);  NT_LOAD(Bx, o1, x4);
    NT_LOAD(Cm, o2, m4);  C_LOAD(Cs, o2, s4);  NT_LOAD(Com, o2, om4);
    NT_LOAD(Cos, o2, os4);  NT_LOAD(Cx, o2, x4);
    NT_LOAD(Dm, o3, m4);  C_LOAD(Ds, o3, s4);  NT_LOAD(Dom, o3, om4);
    NT_LOAD(Dos, o3, os4);  NT_LOAD(Dx, o3, x4);

    VM_WAIT_FENCE(15);
    double lsum = obj4d(Am, As, Aom, Aos, Ax, Aa);
    VM_WAIT_FENCE(10);
    lsum += obj4d(Bm, Bs, Bom, Bos, Bx, Ba);
    VM_WAIT_FENCE(5);
    lsum += obj4d(Cm, Cs, Com, Cos, Cx, Ca);
    VM_WAIT_FENCE(0);
    lsum += obj4d(Dm, Ds, Dom, Dos, Dx, Da);

    // block reduce (8 waves)
    #pragma unroll
    for (int off = 32; off > 0; off >>= 1)
        lsum += __shfl_down(lsum, off, 64);
    if (lane == 0) wsum[wave] = lsum;
    __syncthreads();
    if (tid == 0) {
        double t = 0.0;
        #pragma unroll
        for (int w = 0; w < 8; ++w) t += wsum[w];
        // RELAXED device atomic: no fences, no cache writeback (r1-proven
        // cheap and deterministic-enough: absmax 0.0). Visibility to K2 is
        // guaranteed by the inter-dispatch barrier on the stream.
        __hip_atomic_fetch_add(total, t, __ATOMIC_RELAXED,
                               __HIP_MEMORY_SCOPE_AGENT);
    }
}

// ---------------------------------------------------------------------------
// K2: out[i] = mean + log(sigma[i]) + ENTC.
// Reads ONE f64 (total) instead of a partials array (r5's K2 dragged
// 2048 blocks x 16KB = 32MB of partial re-reads). 8 asm loads in flight
// per thread (proven MLP pattern), one drain, NT stores.
// ---------------------------------------------------------------------------
__global__ __launch_bounds__(256) void out_kernel(
    const float* __restrict__ sigma, const double* __restrict__ total,
    float* __restrict__ out)
{
    const int tid = threadIdx.x;
    const uint32_t Q = (uint32_t)(NTOT / 4 / 8);        // 524,288 f32x4/stream
    const uint32_t v = (uint32_t)blockIdx.x * 256u + (uint32_t)tid;  // < Q
    const f32x4* s4 = (const f32x4*)sigma;
    f32x4* o4 = (f32x4*)out;

    const double tot = *total;                   // uniform; issues first

    f32x4 a0, a1, a2, a3, a4, a5, a6, a7;
    C_LOAD(a0, (v + 0u * Q) * 16u, s4);
    C_LOAD(a1, (v + 1u * Q) * 16u, s4);
    C_LOAD(a2, (v + 2u * Q) * 16u, s4);
    C_LOAD(a3, (v + 3u * Q) * 16u, s4);
    C_LOAD(a4, (v + 4u * Q) * 16u, s4);
    C_LOAD(a5, (v + 5u * Q) * 16u, s4);
    C_LOAD(a6, (v + 6u * Q) * 16u, s4);
    C_LOAD(a7, (v + 7u * Q) * 16u, s4);

    const float mc = (float)(tot / (double)NTOT) + ENTC;   // mean + ENTC

    VM_WAIT_FENCE(0);                            // all 8 streams landed

    f32x4 r0, r1, r2, r3, r4, r5, r6, r7;
    r0.x = mc + __logf(a0.x); r0.y = mc + __logf(a0.y);
    r0.z = mc + __logf(a0.z); r0.w = mc + __logf(a0.w);
    r1.x = mc + __logf(a1.x); r1.y = mc + __logf(a1.y);
    r1.z = mc + __logf(a1.z); r1.w = mc + __logf(a1.w);
    r2.x = mc + __logf(a2.x); r2.y = mc + __logf(a2.y);
    r2.z = mc + __logf(a2.z); r2.w = mc + __logf(a2.w);
    r3.x = mc + __logf(a3.x); r3.y = mc + __logf(a3.y);
    r3.z = mc + __logf(a3.z); r3.w = mc + __logf(a3.w);
    r4.x = mc + __logf(a4.x); r4.y = mc + __logf(a4.y);
    r4.z = mc + __logf(a4.z); r4.w = mc + __logf(a4.w);
    r5.x = mc + __logf(a5.x); r5.y = mc + __logf(a5.y);
    r5.z = mc + __logf(a5.z); r5.w = mc + __logf(a5.w);
    r6.x = mc + __logf(a6.x); r6.y = mc + __logf(a6.y);
    r6.z = mc + __logf(a6.z); r6.w = mc + __logf(a6.w);
    r7.x = mc + __logf(a7.x); r7.y = mc + __logf(a7.y);
    r7.z = mc + __logf(a7.z); r7.w = mc + __logf(a7.w);

    __builtin_nontemporal_store(r0, o4 + v + 0u * Q);
    __builtin_nontemporal_store(r1, o4 + v + 1u * Q);
    __builtin_nontemporal_store(r2, o4 + v + 2u * Q);
    __builtin_nontemporal_store(r3, o4 + v + 3u * Q);
    __builtin_nontemporal_store(r4, o4 + v + 4u * Q);
    __builtin_nontemporal_store(r5, o4 + v + 5u * Q);
    __builtin_nontemporal_store(r6, o4 + v + 6u * Q);
    __builtin_nontemporal_store(r7, o4 + v + 7u * Q);
}

// ---------------------------------------------------------------------------
extern "C" void kernel_launch(void* const* d_in, const int* in_sizes, int n_in,
                              void* d_out, int out_size, void* d_ws, size_t ws_size,
                              hipStream_t stream) {
    const float* rewards   = (const float*)d_in[0];   // [B,T]
    const float* critic    = (const float*)d_in[1];   // [B,T+1]
    const float* mu        = (const float*)d_in[2];   // [B,T,A]
    const float* sigma     = (const float*)d_in[3];
    const float* old_mu    = (const float*)d_in[4];
    const float* old_sigma = (const float*)d_in[5];
    const float* actions   = (const float*)d_in[6];
    const int*   dones     = (const int*)d_in[7];     // [B,T]
    float* out = (float*)d_out;

    double* total = (double*)d_ws;                    // 8 B accumulator

    hipMemsetAsync(total, 0, sizeof(double), stream);
    gae_obj_kernel<<<NB1, 512, 0, stream>>>(rewards, critic, dones,
                                            mu, sigma, old_mu, old_sigma,
                                            actions, total);
    out_kernel<<<NB3, 256, 0, stream>>>(sigma, total, out);
}

// Round 8
// 323.750 us; speedup vs baseline: 1.2951x; 1.0234x over previous
//
#include <hip/hip_runtime.h>
#include <math.h>

// Problem constants
#define BB 512
#define TT 2048
#define AA 16
#define NTOT (512LL * 2048LL * 16LL)   // 16,777,216
#define GAMMA 0.99f
#define GLAM  0.9405f                  // gamma * lam, matches python double->f32
#define ENTC  1.4189385332046727f      // 0.5 + 0.5*log(2*pi)

#define QPB 4                          // blocks per batch row (phase-2 split)
#define NB1 (BB * QPB)                 // 2048 blocks for fused kernel
#define NB3 2048                       // blocks for out kernel (8 f32x4/thread)

typedef float f32x4 __attribute__((ext_vector_type(4)));

// Volatile-asm 16B global loads (proven r5: ordering and liveness immune to
// the source-pipeline collapse seen in r1/r2/r4).
#define NT_LOAD(dst, off, base) \
    asm volatile("global_load_dwordx4 %0, %1, %2 nt" \
                 : "=v"(dst) : "v"(off), "s"(base))
#define C_LOAD(dst, off, base) \
    asm volatile("global_load_dwordx4 %0, %1, %2" \
                 : "=v"(dst) : "v"(off), "s"(base))
#define VM_WAIT_FENCE(n) do { \
    asm volatile("s_waitcnt vmcnt(" #n ")"); \
    __builtin_amdgcn_sched_barrier(0); } while (0)

// ---------------------------------------------------------------------------
__device__ __forceinline__ float obj1(float x, float m, float s,
                                      float om, float os, float ad)
{
    float rs  = __builtin_amdgcn_rcpf(s);
    float ros = __builtin_amdgcn_rcpf(os);
    float z   = (x - m) * rs;
    float zo  = (x - om) * ros;
    float d   = 0.5f * (zo * zo - z * z);
    float ratio = os * rs * __expf(d);
    return fminf(ad * ratio, ad * 0.8f);     // clipped == 0.8 (faithful clip bug)
}

__device__ __forceinline__ double obj4d(f32x4 m, f32x4 s, f32x4 om, f32x4 os,
                                        f32x4 x, float ad)
{
    float o0 = obj1(x.x, m.x, s.x, om.x, os.x, ad);
    float o1 = obj1(x.y, m.y, s.y, om.y, os.y, ad);
    float o2 = obj1(x.z, m.z, s.z, om.z, os.z, ad);
    float o3 = obj1(x.w, m.w, s.w, om.w, os.w, ad);
    return (double)o0 + (double)o1 + (double)o2 + (double)o3;
}

// ---------------------------------------------------------------------------
// K1: FUSED GAE + PPO objective. r5 body EXACTLY (natural blockIdx -- the
// r7 XCD swizzle cut FETCH 188.6->170MB but cost +5us / -15% hbm_gbps:
// contiguous-per-XCD ranges lose HBM channel striping; net loss, reverted).
// Only delta vs r5: relaxed f64 atomic total (r1-proven cheap; removes the
// partials array and K2's 32MB partials re-read. NOT acq_rel -- r6 showed
// per-block release fences emit L2 writebacks, 2.3x regression).
// ---------------------------------------------------------------------------
__global__ __launch_bounds__(512) void gae_obj_kernel(
    const float* __restrict__ rewards, const float* __restrict__ vout,
    const int* __restrict__ dones,
    const float* __restrict__ mu, const float* __restrict__ sigma,
    const float* __restrict__ old_mu, const float* __restrict__ old_sigma,
    const float* __restrict__ actions,
    double* __restrict__ total)
{
    __shared__ float  adv_s[TT];          // 8 KB
    __shared__ float  wA[8], wB[8];
    __shared__ double wsum[8];

    const int b    = blockIdx.x >> 2;     // batch row (natural order)
    const int q    = blockIdx.x & 3;      // quarter of the row
    const int tid  = threadIdx.x;
    const int lane = tid & 63;
    const int wave = tid >> 6;

    // ---------------- Phase 1: full-row GAE scan into LDS ----------------
    {
        const float* rw = rewards + (size_t)b * TT;
        const float* V  = vout    + (size_t)b * (TT + 1);
        const int*   dn = dones   + (size_t)b * TT;

        const int t_lo = TT - 4 - 4 * tid;          // multiple of 4, >= 0

        f32x4 r4 = *(const f32x4*)(rw + t_lo);
        int4  d4 = *(const int4*)(dn + t_lo);
        int   dt = (tid == 0) ? 1 : dn[t_lo + 4];   // dn[2048] OOB for tid 0; unused there
        float vv[5];
        #pragma unroll
        for (int j = 0; j < 5; ++j) vv[j] = V[t_lo + j];  // V[2048] valid (T+1 cols)

        float rr[4] = {r4.x, r4.y, r4.z, r4.w};
        int   dd[5] = {d4.x, d4.y, d4.z, d4.w, dt};

        float ak[4], bk[4];
        float SA = 1.f, SB = 0.f;                   // segment composite (earliest-first)
        #pragma unroll
        for (int k = 0; k < 4; ++k) {
            // u = tid*4 + k ; t = TT-1-u = t_lo + (3-k)
            const int j = 3 - k;
            float bu = rr[j] + GAMMA * vv[j + 1] - vv[j];
            float au = GLAM * (1.f - (float)dd[j + 1]);
            if (k == 0 && tid == 0) { au = 0.f; bu = 0.f; }   // u == 0
            ak[k] = au; bk[k] = bu;
            SB = au * SB + bu;
            SA = au * SA;
        }

        #pragma unroll
        for (int off = 1; off < 64; off <<= 1) {
            float pA = __shfl_up(SA, off, 64);
            float pB = __shfl_up(SB, off, 64);
            if (lane >= off) { SB = SA * pB + SB; SA = SA * pA; }
        }

        if (lane == 63) { wA[wave] = SA; wB[wave] = SB; }
        __syncthreads();

        float PA = 1.f, PB = 0.f;
        for (int w = 0; w < wave; ++w) {
            float aw = wA[w], bw = wB[w];
            PB = aw * PB + bw;
            PA = aw * PA;
        }

        float EA = __shfl_up(SA, 1, 64);
        float EB = __shfl_up(SB, 1, 64);
        if (lane == 0) { EA = 1.f; EB = 0.f; }

        float x = EA * PB + EB;
        float outb[4];
        #pragma unroll
        for (int k = 0; k < 4; ++k) {
            x = ak[k] * x + bk[k];
            outb[3 - k] = x;                        // t = t_lo + (3-k)
        }
        *(f32x4*)(adv_s + t_lo) = (f32x4){outb[0], outb[1], outb[2], outb[3]};
    }
    __syncthreads();

    // ---------------- Phase 2: objective over this block's quarter --------
    const size_t basef4 = (size_t)b * 8192 + (size_t)q * 2048;
    const f32x4* m4  = (const f32x4*)mu        + basef4;
    const f32x4* s4  = (const f32x4*)sigma     + basef4;
    const f32x4* om4 = (const f32x4*)old_mu    + basef4;
    const f32x4* os4 = (const f32x4*)old_sigma + basef4;
    const f32x4* x4  = (const f32x4*)actions   + basef4;
    const float* advq = adv_s + q * 512;

    const int ai = tid >> 2;
    const float Aa = advq[ai];
    const float Ba = advq[ai + 128];
    const float Ca = advq[ai + 256];
    const float Da = advq[ai + 384];

    const uint32_t o0 = (uint32_t)tid * 16u;
    const uint32_t o1 = o0 + 512u * 16u;
    const uint32_t o2 = o0 + 1024u * 16u;
    const uint32_t o3 = o0 + 1536u * 16u;

    f32x4 Am, As, Aom, Aos, Ax;
    f32x4 Bm, Bs, Bom, Bos, Bx;
    f32x4 Cm, Cs, Com, Cos, Cx;
    f32x4 Dm, Ds, Dom, Dos, Dx;

    // 20 loads in flight per thread; sigma cached (reused by K2), rest NT
    NT_LOAD(Am, o0, m4);  C_LOAD(As, o0, s4);  NT_LOAD(Aom, o0, om4);
    NT_LOAD(Aos, o0, os4);  NT_LOAD(Ax, o0, x4);
    NT_LOAD(Bm, o1, m4);  C_LOAD(Bs, o1, s4);  NT_LOAD(Bom, o1, om4);
    NT_LOAD(Bos, o1, os4);  NT_LOAD(Bx, o1, x4);
    NT_LOAD(Cm, o2, m4);  C_LOAD(Cs, o2, s4);  NT_LOAD(Com, o2, om4);
    NT_LOAD(Cos, o2, os4);  NT_LOAD(Cx, o2, x4);
    NT_LOAD(Dm, o3, m4);  C_LOAD(Ds, o3, s4);  NT_LOAD(Dom, o3, om4);
    NT_LOAD(Dos, o3, os4);  NT_LOAD(Dx, o3, x4);

    VM_WAIT_FENCE(15);
    double lsum = obj4d(Am, As, Aom, Aos, Ax, Aa);
    VM_WAIT_FENCE(10);
    lsum += obj4d(Bm, Bs, Bom, Bos, Bx, Ba);
    VM_WAIT_FENCE(5);
    lsum += obj4d(Cm, Cs, Com, Cos, Cx, Ca);
    VM_WAIT_FENCE(0);
    lsum += obj4d(Dm, Ds, Dom, Dos, Dx, Da);

    // block reduce (8 waves)
    #pragma unroll
    for (int off = 32; off > 0; off >>= 1)
        lsum += __shfl_down(lsum, off, 64);
    if (lane == 0) wsum[wave] = lsum;
    __syncthreads();
    if (tid == 0) {
        double t = 0.0;
        #pragma unroll
        for (int w = 0; w < 8; ++w) t += wsum[w];
        // RELAXED device atomic: no fences, no cache writeback. Visibility
        // to K2 is guaranteed by the inter-dispatch barrier on the stream.
        __hip_atomic_fetch_add(total, t, __ATOMIC_RELAXED,
                               __HIP_MEMORY_SCOPE_AGENT);
    }
}

// ---------------------------------------------------------------------------
// K2: out[i] = mean + log(sigma[i]) + ENTC.
// Reads ONE f64 (total). 8 asm loads in flight per thread, one drain,
// NT stores. sigma is L3-warm from K1's cached loads.
// ---------------------------------------------------------------------------
__global__ __launch_bounds__(256) void out_kernel(
    const float* __restrict__ sigma, const double* __restrict__ total,
    float* __restrict__ out)
{
    const int tid = threadIdx.x;
    const uint32_t Q = (uint32_t)(NTOT / 4 / 8);        // 524,288 f32x4/stream
    const uint32_t v = (uint32_t)blockIdx.x * 256u + (uint32_t)tid;  // < Q
    const f32x4* s4 = (const f32x4*)sigma;
    f32x4* o4 = (f32x4*)out;

    const double tot = *total;                   // uniform s_load

    f32x4 a0, a1, a2, a3, a4, a5, a6, a7;
    C_LOAD(a0, (v + 0u * Q) * 16u, s4);
    C_LOAD(a1, (v + 1u * Q) * 16u, s4);
    C_LOAD(a2, (v + 2u * Q) * 16u, s4);
    C_LOAD(a3, (v + 3u * Q) * 16u, s4);
    C_LOAD(a4, (v + 4u * Q) * 16u, s4);
    C_LOAD(a5, (v + 5u * Q) * 16u, s4);
    C_LOAD(a6, (v + 6u * Q) * 16u, s4);
    C_LOAD(a7, (v + 7u * Q) * 16u, s4);

    const float mc = (float)(tot / (double)NTOT) + ENTC;   // mean + ENTC

    VM_WAIT_FENCE(0);                            // all 8 streams landed

    f32x4 r0, r1, r2, r3, r4, r5, r6, r7;
    r0.x = mc + __logf(a0.x); r0.y = mc + __logf(a0.y);
    r0.z = mc + __logf(a0.z); r0.w = mc + __logf(a0.w);
    r1.x = mc + __logf(a1.x); r1.y = mc + __logf(a1.y);
    r1.z = mc + __logf(a1.z); r1.w = mc + __logf(a1.w);
    r2.x = mc + __logf(a2.x); r2.y = mc + __logf(a2.y);
    r2.z = mc + __logf(a2.z); r2.w = mc + __logf(a2.w);
    r3.x = mc + __logf(a3.x); r3.y = mc + __logf(a3.y);
    r3.z = mc + __logf(a3.z); r3.w = mc + __logf(a3.w);
    r4.x = mc + __logf(a4.x); r4.y = mc + __logf(a4.y);
    r4.z = mc + __logf(a4.z); r4.w = mc + __logf(a4.w);
    r5.x = mc + __logf(a5.x); r5.y = mc + __logf(a5.y);
    r5.z = mc + __logf(a5.z); r5.w = mc + __logf(a5.w);
    r6.x = mc + __logf(a6.x); r6.y = mc + __logf(a6.y);
    r6.z = mc + __logf(a6.z); r6.w = mc + __logf(a6.w);
    r7.x = mc + __logf(a7.x); r7.y = mc + __logf(a7.y);
    r7.z = mc + __logf(a7.z); r7.w = mc + __logf(a7.w);

    __builtin_nontemporal_store(r0, o4 + v + 0u * Q);
    __builtin_nontemporal_store(r1, o4 + v + 1u * Q);
    __builtin_nontemporal_store(r2, o4 + v + 2u * Q);
    __builtin_nontemporal_store(r3, o4 + v + 3u * Q);
    __builtin_nontemporal_store(r4, o4 + v + 4u * Q);
    __builtin_nontemporal_store(r5, o4 + v + 5u * Q);
    __builtin_nontemporal_store(r6, o4 + v + 6u * Q);
    __builtin_nontemporal_store(r7, o4 + v + 7u * Q);
}

// ---------------------------------------------------------------------------
extern "C" void kernel_launch(void* const* d_in, const int* in_sizes, int n_in,
                              void* d_out, int out_size, void* d_ws, size_t ws_size,
                              hipStream_t stream) {
    const float* rewards   = (const float*)d_in[0];   // [B,T]
    const float* critic    = (const float*)d_in[1];   // [B,T+1]
    const float* mu        = (const float*)d_in[2];   // [B,T,A]
    const float* sigma     = (const float*)d_in[3];
    const float* old_mu    = (const float*)d_in[4];
    const float* old_sigma = (const float*)d_in[5];
    const float* actions   = (const float*)d_in[6];
    const int*   dones     = (const int*)d_in[7];     // [B,T]
    float* out = (float*)d_out;

    double* total = (double*)d_ws;                    // 8 B accumulator

    hipMemsetAsync(total, 0, sizeof(double), stream);
    gae_obj_kernel<<<NB1, 512, 0, stream>>>(rewards, critic, dones,
                                            mu, sigma, old_mu, old_sigma,
                                            actions, total);
    out_kernel<<<NB3, 256, 0, stream>>>(sigma, total, out);
}